// Round 1
// baseline (345.671 us; speedup 1.0000x reference)
//
#include <hip/hip_runtime.h>

typedef unsigned int u32;
typedef unsigned long long u64;

#define NB 10
#define BLOCKS 4096
#define TPB 256          // 4 waves, no bulk LDS -> occupancy VGPR-limited only

// ws layout: bin b owns cache line at u32 index 32*b:
//   [32b+0..1] u64 sum(ffx), [32b+2] count, [32b+3] positives
__global__ void rd_zero_ws(u32* __restrict__ ws) {
    if (threadIdx.x < 320) ws[threadIdx.x] = 0u;
}

// Per element: sigmoid -> bin -> 4 packed u64 register accumulators.
// 6-bit count/pos fields (<=63 elems per unpack window), 12-bit conf-frac
// fields in 7-bit fixed point (<=32 elems per window: 32*127=4064<4095).
__device__ __forceinline__ void rd_acc(float x, int lab,
                                       u64& c64, u64& p64, u64& flo, u64& fhi) {
    float e = __expf(-x);
    float conf = __builtin_amdgcn_rcpf(1.0f + e);        // sigmoid
    float t10 = __builtin_fmaf(conf, 10.0f, -1e-6f);     // bins are (l,u]
    int b = min(9, (int)t10);
    float frac = t10 - (float)b;                         // [0,1)
    u32 ffx = (u32)__builtin_fmaf(frac, 127.0f, 0.5f);   // 7-bit fixed point

    u32 sh6 = (u32)(b * 6);
    c64 += 1ull << sh6;                                  // 6-bit count fields
    p64 += ((u64)(u32)lab) << sh6;                       // 6-bit positive fields

    bool lo = b < 5;
    u32 sh12 = (u32)(b * 12);
    u32 shf = lo ? sh12 : (sh12 - 60u);
    u64 v = ((u64)ffx) << shf;                           // 12-bit fields, 5 per u64
    flo += lo ? v : 0ull;
    fhi += lo ? 0ull : v;
}

__device__ __forceinline__ void rd_acc4(const float4& x, const int4& y,
                                        u64& c64, u64& p64, u64& flo, u64& fhi) {
    rd_acc(x.x, y.x, c64, p64, flo, fhi);
    rd_acc(x.y, y.y, c64, p64, flo, fhi);
    rd_acc(x.z, y.z, c64, p64, flo, fhi);
    rd_acc(x.w, y.w, c64, p64, flo, fhi);
}

// Pure streaming: no reuse -> no LDS staging. Coalesced grid-stride float4/int4
// loads straight to VGPRs, 4-deep unroll = 8 independent 16B loads in flight
// per thread; the compiler software-pipelines them across the VALU work.
__global__ __launch_bounds__(TPB) void rd_hist(const float* __restrict__ logits,
                                               const int* __restrict__ labels,
                                               u32* __restrict__ ws,
                                               long long n) {
    u32 cp[NB], cf[NB];
    #pragma unroll
    for (int b = 0; b < NB; ++b) { cp[b] = 0u; cf[b] = 0u; }

    const float4* l4 = (const float4*)logits;
    const int4*   i4 = (const int4*)labels;
    long long nf4 = n >> 2;
    long long tid = (long long)blockIdx.x * TPB + threadIdx.x;
    long long stride = (long long)gridDim.x * TPB;

    u64 c64 = 0, p64 = 0, flo = 0, fhi = 0;
    int pend = 0;   // elements currently folded into the packed accumulators

    #define UNPACK() do {                                                   \
        _Pragma("unroll")                                                   \
        for (int b = 0; b < NB; ++b) {                                      \
            u32 cnt = (u32)(c64 >> (6 * b)) & 63u;                          \
            u32 pos = (u32)(p64 >> (6 * b)) & 63u;                          \
            cp[b] += cnt | (pos << 16);                                     \
            cf[b] += (b < 5) ? ((u32)(flo >> (12 * b)) & 4095u)             \
                             : ((u32)(fhi >> (12 * (b - 5))) & 4095u);      \
        }                                                                   \
        c64 = 0; p64 = 0; flo = 0; fhi = 0;                                 \
    } while (0)

    long long i = tid;
    // main loop: 16 elems/iter; unpack every 2 iters (32 elems, field-safe)
    for (; i + 3 * stride < nf4; i += 4 * stride) {
        float4 x0 = l4[i];
        float4 x1 = l4[i + stride];
        float4 x2 = l4[i + 2 * stride];
        float4 x3 = l4[i + 3 * stride];
        int4   y0 = i4[i];
        int4   y1 = i4[i + stride];
        int4   y2 = i4[i + 2 * stride];
        int4   y3 = i4[i + 3 * stride];
        rd_acc4(x0, y0, c64, p64, flo, fhi);
        rd_acc4(x1, y1, c64, p64, flo, fhi);
        rd_acc4(x2, y2, c64, p64, flo, fhi);
        rd_acc4(x3, y3, c64, p64, flo, fhi);
        pend += 16;
        if (pend == 32) { UNPACK(); pend = 0; }
    }
    // float4 remainder (pend stays a multiple of 4, hits 32 exactly)
    for (; i < nf4; i += stride) {
        float4 x = l4[i];
        int4   y = i4[i];
        rd_acc4(x, y, c64, p64, flo, fhi);
        pend += 4;
        if (pend == 32) { UNPACK(); pend = 0; }
    }
    // scalar tail for n % 4 (empty at N=2^25)
    long long base = nf4 << 2;
    for (long long j = base + tid; j < n; j += stride) {
        rd_acc(logits[j], labels[j], c64, p64, flo, fhi);
        if (++pend == 32) { UNPACK(); pend = 0; }
    }
    if (pend) UNPACK();
    #undef UNPACK

    // wave reduce + block combine (LDS: 320 B only)
    __shared__ u32 s_cp[TPB / 64][NB];
    __shared__ u32 s_cf[TPB / 64][NB];
    int lane = threadIdx.x & 63;
    int wave = threadIdx.x >> 6;
    #pragma unroll
    for (int b = 0; b < NB; ++b) {
        u32 c = cp[b];                 // per-thread count <= 32 -> 16-bit safe
        u32 f = cf[b];
        #pragma unroll
        for (int off = 32; off; off >>= 1) {
            c += __shfl_down(c, off, 64);
            f += __shfl_down(f, off, 64);
        }
        if (lane == 0) { s_cp[wave][b] = c; s_cf[wave][b] = f; }
    }
    __syncthreads();

    if (threadIdx.x < NB) {
        int b = threadIdx.x;
        u32 c = 0; u64 f = 0;
        #pragma unroll
        for (int w = 0; w < TPB / 64; ++w) { c += s_cp[w][b]; f += s_cf[w][b]; }
        atomicAdd((u64*)&ws[32 * b], f);
        atomicAdd(&ws[32 * b + 2], c & 0xFFFFu);
        atomicAdd(&ws[32 * b + 3], c >> 16);
    }
}

__global__ void rd_finalize(const u32* __restrict__ ws, float* __restrict__ out) {
    int b = threadIdx.x;
    if (b < NB) {
        u64 f   = *(const u64*)&ws[32 * b];
        u32 cnt = ws[32 * b + 2];
        u32 pos = ws[32 * b + 3];
        double sumconf = ((double)b * (double)cnt + (double)f * (1.0 / 127.0)) * 0.1;
        float denom = fmaxf((float)cnt, 1.0f);
        bool ne = cnt > 0u;
        out[b]      = ne ? ((float)pos / denom) : 0.0f;
        out[NB + b] = ne ? (float)(sumconf / (double)denom) : 0.0f;
    }
}

extern "C" void kernel_launch(void* const* d_in, const int* in_sizes, int n_in,
                              void* d_out, int out_size, void* d_ws, size_t ws_size,
                              hipStream_t stream) {
    const float* logits = (const float*)d_in[0];
    const int*   labels = (const int*)d_in[1];
    float* out = (float*)d_out;
    u32*   ws  = (u32*)d_ws;
    long long n = (long long)in_sizes[0];

    rd_zero_ws<<<1, 512, 0, stream>>>(ws);
    rd_hist<<<BLOCKS, TPB, 0, stream>>>(logits, labels, ws, n);
    rd_finalize<<<1, 64, 0, stream>>>(ws, out);
}

// Round 2
// 305.964 us; speedup vs baseline: 1.1298x; 1.1298x over previous
//
#include <hip/hip_runtime.h>

typedef unsigned int u32;
typedef unsigned long long u64;

#define NB 10
#define BLOCKS 2048
#define TPB 256           // 4 waves
#define ITERS 16
#define CHUNK_F4 64       // float4 per wave per iteration (= 1 dma16 per array)
#define WAVE_F4 (ITERS * CHUNK_F4)   // 1024 contiguous float4 per wave

typedef __attribute__((address_space(3))) char lds_char;
typedef __attribute__((address_space(1))) const char g_char;

__device__ __forceinline__ void dma16(const void* g, void* l) {
    // async global->LDS, 16 B/lane: LDS dest = wave-uniform base + lane*16
    __builtin_amdgcn_global_load_lds((g_char*)g, (lds_char*)l, 16, 0, 0);
}

// gfx9 waitcnt encoding: vmcnt[3:0]|[15:14], expcnt[6:4], lgkmcnt[11:8]
#define WAIT_VM(nn)  __builtin_amdgcn_s_waitcnt(((nn) & 15) | 0xF70)  // lgkm/exp don't-care
#define WAIT_LGKM0() __builtin_amdgcn_s_waitcnt(0xC07F)               // vm don't-care, lgkm=0

#if defined(__has_builtin)
#if __has_builtin(__builtin_amdgcn_sched_barrier)
#define SCHEDB() __builtin_amdgcn_sched_barrier(0)
#else
#define SCHEDB()
#endif
#else
#define SCHEDB()
#endif

// ws layout: bin b owns cache line at u32 index 32*b:
//   [32b+0..1] u64 sum(ffx), [32b+2] count, [32b+3] positives
__global__ void rd_zero_ws(u32* __restrict__ ws) {
    if (threadIdx.x < 320) ws[threadIdx.x] = 0u;
}

// Per element: sigmoid -> bin -> 4 packed u64 register accumulators.
__device__ __forceinline__ void rd_acc(float x, int lab,
                                       u64& c64, u64& p64, u64& flo, u64& fhi) {
    float e = __expf(-x);
    float conf = __builtin_amdgcn_rcpf(1.0f + e);        // sigmoid
    float t10 = __builtin_fmaf(conf, 10.0f, -1e-6f);     // bins are (l,u]
    int b = min(9, (int)t10);
    float frac = t10 - (float)b;                         // [0,1)
    u32 ffx = (u32)__builtin_fmaf(frac, 127.0f, 0.5f);   // 7-bit fixed point

    u32 sh6 = (u32)(b * 6);
    c64 += 1ull << sh6;                                  // 6-bit count fields
    p64 += ((u64)(u32)lab) << sh6;                       // 6-bit positive fields

    bool lo = b < 5;
    u32 sh12 = (u32)(b * 12);
    u32 shf = lo ? sh12 : (sh12 - 60u);
    u64 v = ((u64)ffx) << shf;                           // 12-bit fields, 5 per u64
    flo += lo ? v : 0ull;
    fhi += lo ? 0ull : v;
}

__device__ __forceinline__ void rd_acc4(const float4& x, const int4& y,
                                        u64& c64, u64& p64, u64& flo, u64& fhi) {
    rd_acc(x.x, y.x, c64, p64, flo, fhi);
    rd_acc(x.y, y.y, c64, p64, flo, fhi);
    rd_acc(x.z, y.z, c64, p64, flo, fhi);
    rd_acc(x.w, y.w, c64, p64, flo, fhi);
}

// Proven structure (r0: 120us): global_load_lds double-buffer w/ counted vmcnt.
// r2 change: halve chunk -> 4 KB LDS/wave -> 16 KB/block -> 8 blocks/CU
// co-resident = 32 waves/CU (2x TLP at same pipeline discipline); persistent
// blocks (ITERS=16, one generation) so the pipeline ramps/drains once.
__global__ __launch_bounds__(TPB) void rd_hist(const float* __restrict__ logits,
                                               const int* __restrict__ labels,
                                               u32* __restrict__ ws,
                                               long long n) {
    // per wave 4 KB: buf{0,1} x (1 KB logits + 1 KB labels); 4 waves = 16 KB
    __shared__ __align__(16) char lds[16 * 1024];

    u32 cp[NB], cf[NB];
    #pragma unroll
    for (int b = 0; b < NB; ++b) { cp[b] = 0u; cf[b] = 0u; }

    const float4* l4 = (const float4*)logits;
    const int4*   i4 = (const int4*)labels;
    int lane = threadIdx.x & 63;
    int wave = threadIdx.x >> 6;
    long long nf4 = n >> 2;
    long long seg = (long long)blockIdx.x * (4 * WAVE_F4);

    if (seg + 4 * WAVE_F4 <= nf4) {
        long long gb = seg + (long long)wave * WAVE_F4;
        const float4* gl = l4 + gb + lane;
        const int4*   gi = i4 + gb + lane;
        char* myl = lds + wave * 4096;

        #define ISSUE(t, bb) do {                               \
            char* _base = myl + (bb) * 2048;                    \
            dma16(gl + (t) * CHUNK_F4, _base);                  \
            dma16(gi + (t) * CHUNK_F4, _base + 1024);           \
        } while (0)

        ISSUE(0, 0);
        ISSUE(1, 1);

        u64 c64 = 0, p64 = 0, flo = 0, fhi = 0;
        #pragma unroll
        for (int t = 0; t < ITERS; ++t) {
            const int bb = t & 1;
            const char* base = myl + bb * 2048;
            if (t < ITERS - 1) { WAIT_VM(2); } else { WAIT_VM(0); }
            SCHEDB();
            float4 xa = *(const float4*)(base + lane * 16);
            int4   ya = *(const int4*)(base + 1024 + lane * 16);
            WAIT_LGKM0();                 // reads landed in VGPRs -> buffer reusable
            SCHEDB();
            if (t + 2 < ITERS) ISSUE(t + 2, bb);
            SCHEDB();
            rd_acc4(xa, ya, c64, p64, flo, fhi);
            if ((t & 7) == 7) {           // unpack every 32 elems (field-safe)
                #pragma unroll
                for (int b = 0; b < NB; ++b) {
                    u32 cnt = (u32)(c64 >> (6 * b)) & 63u;
                    u32 pos = (u32)(p64 >> (6 * b)) & 63u;
                    cp[b] += cnt | (pos << 16);
                    cf[b] += (b < 5) ? ((u32)(flo >> (12 * b)) & 4095u)
                                     : ((u32)(fhi >> (12 * (b - 5))) & 4095u);
                }
                c64 = 0; p64 = 0; flo = 0; fhi = 0;
            }
        }
        #undef ISSUE
    }

    // generic tail (empty at N=2^25): direct atomics, rarely runs
    long long done_f4 = ((long long)gridDim.x < nf4 / (4 * WAVE_F4)
                             ? (long long)gridDim.x
                             : nf4 / (4 * WAVE_F4)) * (4 * WAVE_F4);
    long long tail = done_f4 * 4;
    if (tail < n) {
        long long tid    = (long long)blockIdx.x * blockDim.x + threadIdx.x;
        long long stride = (long long)gridDim.x * blockDim.x;
        for (long long i = tail + tid; i < n; i += stride) {
            float e = __expf(-logits[i]);
            float conf = __builtin_amdgcn_rcpf(1.0f + e);
            float t10 = __builtin_fmaf(conf, 10.0f, -1e-6f);
            int b = min(9, (int)t10);
            float frac = t10 - (float)b;
            u32 ffx = (u32)__builtin_fmaf(frac, 127.0f, 0.5f);
            atomicAdd((u64*)&ws[32 * b], (u64)ffx);
            atomicAdd(&ws[32 * b + 2], 1u);
            atomicAdd(&ws[32 * b + 3], (u32)labels[i]);
        }
    }

    // wave reduce + block combine
    __shared__ u32 s_cp[4][NB];
    __shared__ u32 s_cf[4][NB];
    #pragma unroll
    for (int b = 0; b < NB; ++b) {
        u32 c = cp[b];                      // thread sums <= 64 -> 16-bit safe
        u32 f = cf[b];
        #pragma unroll
        for (int off = 32; off; off >>= 1) {
            c += __shfl_down(c, off, 64);
            f += __shfl_down(f, off, 64);
        }
        if (lane == 0) { s_cp[wave][b] = c; s_cf[wave][b] = f; }
    }
    __syncthreads();

    if (threadIdx.x < NB) {
        int b = threadIdx.x;
        u32 c = s_cp[0][b] + s_cp[1][b] + s_cp[2][b] + s_cp[3][b];  // fields <= 16384
        u64 f = (u64)s_cf[0][b] + s_cf[1][b] + s_cf[2][b] + s_cf[3][b];
        atomicAdd((u64*)&ws[32 * b], f);
        atomicAdd(&ws[32 * b + 2], c & 0xFFFFu);
        atomicAdd(&ws[32 * b + 3], c >> 16);
    }
}

__global__ void rd_finalize(const u32* __restrict__ ws, float* __restrict__ out) {
    int b = threadIdx.x;
    if (b < NB) {
        u64 f   = *(const u64*)&ws[32 * b];
        u32 cnt = ws[32 * b + 2];
        u32 pos = ws[32 * b + 3];
        double sumconf = ((double)b * (double)cnt + (double)f * (1.0 / 127.0)) * 0.1;
        float denom = fmaxf((float)cnt, 1.0f);
        bool ne = cnt > 0u;
        out[b]      = ne ? ((float)pos / denom) : 0.0f;
        out[NB + b] = ne ? (float)(sumconf / (double)denom) : 0.0f;
    }
}

extern "C" void kernel_launch(void* const* d_in, const int* in_sizes, int n_in,
                              void* d_out, int out_size, void* d_ws, size_t ws_size,
                              hipStream_t stream) {
    const float* logits = (const float*)d_in[0];
    const int*   labels = (const int*)d_in[1];
    float* out = (float*)d_out;
    u32*   ws  = (u32*)d_ws;
    long long n = (long long)in_sizes[0];

    rd_zero_ws<<<1, 512, 0, stream>>>(ws);
    rd_hist<<<BLOCKS, TPB, 0, stream>>>(logits, labels, ws, n);
    rd_finalize<<<1, 64, 0, stream>>>(ws, out);
}

// Round 3
// 296.107 us; speedup vs baseline: 1.1674x; 1.0333x over previous
//
#include <hip/hip_runtime.h>

typedef unsigned int u32;
typedef unsigned long long u64;

#define NB 10
#define BLOCKS 1024       // 4 blocks/CU -> one generation, all resident
#define TPB 256           // 4 waves
#define ITERS 32          // float4 batches per thread
#define DEPTH 4           // register pipeline depth (batches in flight)
#define WAVE_F4 (ITERS * 64)   // 2048 contiguous float4 per wave

// ws layout: bin b owns cache line at u32 index 32*b:
//   [32b+0..1] u64 sum(ffx), [32b+2] count, [32b+3] positives
__global__ void rd_zero_ws(u32* __restrict__ ws) {
    if (threadIdx.x < 320) ws[threadIdx.x] = 0u;
}

// Per element: sigmoid -> bin -> 4 packed u64 register accumulators.
// 6-bit count/pos fields; 12-bit conf-frac fields (7-bit fixed point),
// unpack window 32 elems: 32*127 = 4064 < 4095 (field-safe).
__device__ __forceinline__ void rd_acc(float x, int lab,
                                       u64& c64, u64& p64, u64& flo, u64& fhi) {
    float e = __expf(-x);
    float conf = __builtin_amdgcn_rcpf(1.0f + e);        // sigmoid
    float t10 = __builtin_fmaf(conf, 10.0f, -1e-6f);     // bins are (l,u]
    int b = min(9, (int)t10);
    float frac = t10 - (float)b;                         // [0,1)
    u32 ffx = (u32)__builtin_fmaf(frac, 127.0f, 0.5f);   // 7-bit fixed point

    u32 sh6 = (u32)(b * 6);
    c64 += 1ull << sh6;                                  // 6-bit count fields
    p64 += ((u64)(u32)lab) << sh6;                       // 6-bit positive fields

    bool lo = b < 5;
    u32 sh12 = (u32)(b * 12);
    u32 shf = lo ? sh12 : (sh12 - 60u);
    u64 v = ((u64)ffx) << shf;                           // 12-bit fields, 5 per u64
    flo += lo ? v : 0ull;
    fhi += lo ? 0ull : v;
}

__device__ __forceinline__ void rd_acc4(const float4& x, const int4& y,
                                        u64& c64, u64& p64, u64& flo, u64& fhi) {
    rd_acc(x.x, y.x, c64, p64, flo, fhi);
    rd_acc(x.y, y.y, c64, p64, flo, fhi);
    rd_acc(x.z, y.z, c64, p64, flo, fhi);
    rd_acc(x.w, y.w, c64, p64, flo, fhi);
}

// Register-resident software pipeline: contiguous per-wave segments, plain
// dwordx4 loads into a DEPTH-4 statically-rotated register ring. Refills are
// issued BEFORE each step's compute, so DEPTH-1 batches are always in flight
// while the VALU works — no LDS round-trip, in-flight bytes live in VGPRs.
__global__ __launch_bounds__(TPB, 4) void rd_hist(const float* __restrict__ logits,
                                                  const int* __restrict__ labels,
                                                  u32* __restrict__ ws,
                                                  long long n) {
    u32 cp[NB], cf[NB];
    #pragma unroll
    for (int b = 0; b < NB; ++b) { cp[b] = 0u; cf[b] = 0u; }

    const float4* l4 = (const float4*)logits;
    const int4*   i4 = (const int4*)labels;
    int lane = threadIdx.x & 63;
    int wave = threadIdx.x >> 6;
    long long nf4 = n >> 2;
    long long seg = (long long)blockIdx.x * (4 * WAVE_F4);

    u64 c64 = 0, p64 = 0, flo = 0, fhi = 0;

    #define UNPACK() do {                                                   \
        _Pragma("unroll")                                                   \
        for (int b = 0; b < NB; ++b) {                                      \
            u32 cnt = (u32)(c64 >> (6 * b)) & 63u;                          \
            u32 pos = (u32)(p64 >> (6 * b)) & 63u;                          \
            cp[b] += cnt | (pos << 16);                                     \
            cf[b] += (b < 5) ? ((u32)(flo >> (12 * b)) & 4095u)             \
                             : ((u32)(fhi >> (12 * (b - 5))) & 4095u);      \
        }                                                                   \
        c64 = 0; p64 = 0; flo = 0; fhi = 0;                                 \
    } while (0)

    if (seg + 4 * WAVE_F4 <= nf4) {
        long long gb = seg + (long long)wave * WAVE_F4;
        const float4* gl = l4 + gb + lane;
        const int4*   gi = i4 + gb + lane;

        // prologue: fill the ring (4 batches = 8 independent 16 B loads)
        float4 px0 = gl[0 * 64], px1 = gl[1 * 64], px2 = gl[2 * 64], px3 = gl[3 * 64];
        int4   py0 = gi[0 * 64], py1 = gi[1 * 64], py2 = gi[2 * 64], py3 = gi[3 * 64];

        #pragma unroll
        for (int t = 0; t < ITERS; ++t) {
            const int s = t & 3;            // static after unroll
            float4 x; int4 y;
            if      (s == 0) { x = px0; y = py0; }
            else if (s == 1) { x = px1; y = py1; }
            else if (s == 2) { x = px2; y = py2; }
            else             { x = px3; y = py3; }
            if (t + DEPTH < ITERS) {        // refill freed slot BEFORE compute
                if      (s == 0) { px0 = gl[(t + DEPTH) * 64]; py0 = gi[(t + DEPTH) * 64]; }
                else if (s == 1) { px1 = gl[(t + DEPTH) * 64]; py1 = gi[(t + DEPTH) * 64]; }
                else if (s == 2) { px2 = gl[(t + DEPTH) * 64]; py2 = gi[(t + DEPTH) * 64]; }
                else             { px3 = gl[(t + DEPTH) * 64]; py3 = gi[(t + DEPTH) * 64]; }
            }
            rd_acc4(x, y, c64, p64, flo, fhi);
            if ((t & 7) == 7) UNPACK();     // every 32 elems, field-safe
        }
    }

    // generic tail (empty at N=2^25): direct atomics, rarely runs
    long long done_f4 = ((long long)gridDim.x < nf4 / (4 * WAVE_F4)
                             ? (long long)gridDim.x
                             : nf4 / (4 * WAVE_F4)) * (4 * WAVE_F4);
    long long tail = done_f4 * 4;
    if (tail < n) {
        long long tid    = (long long)blockIdx.x * blockDim.x + threadIdx.x;
        long long stride = (long long)gridDim.x * blockDim.x;
        for (long long i = tail + tid; i < n; i += stride) {
            float e = __expf(-logits[i]);
            float conf = __builtin_amdgcn_rcpf(1.0f + e);
            float t10 = __builtin_fmaf(conf, 10.0f, -1e-6f);
            int b = min(9, (int)t10);
            float frac = t10 - (float)b;
            u32 ffx = (u32)__builtin_fmaf(frac, 127.0f, 0.5f);
            atomicAdd((u64*)&ws[32 * b], (u64)ffx);
            atomicAdd(&ws[32 * b + 2], 1u);
            atomicAdd(&ws[32 * b + 3], (u32)labels[i]);
        }
    }
    #undef UNPACK

    // wave reduce + block combine (LDS: 320 B total)
    __shared__ u32 s_cp[4][NB];
    __shared__ u32 s_cf[4][NB];
    #pragma unroll
    for (int b = 0; b < NB; ++b) {
        u32 c = cp[b];                  // per-thread count <= 128 -> 16-bit safe
        u32 f = cf[b];
        #pragma unroll
        for (int off = 32; off; off >>= 1) {
            c += __shfl_down(c, off, 64);
            f += __shfl_down(f, off, 64);
        }
        if (lane == 0) { s_cp[wave][b] = c; s_cf[wave][b] = f; }
    }
    __syncthreads();

    if (threadIdx.x < NB) {
        int b = threadIdx.x;
        u32 c = s_cp[0][b] + s_cp[1][b] + s_cp[2][b] + s_cp[3][b];
        u64 f = (u64)s_cf[0][b] + s_cf[1][b] + s_cf[2][b] + s_cf[3][b];
        atomicAdd((u64*)&ws[32 * b], f);
        atomicAdd(&ws[32 * b + 2], c & 0xFFFFu);
        atomicAdd(&ws[32 * b + 3], c >> 16);
    }
}

__global__ void rd_finalize(const u32* __restrict__ ws, float* __restrict__ out) {
    int b = threadIdx.x;
    if (b < NB) {
        u64 f   = *(const u64*)&ws[32 * b];
        u32 cnt = ws[32 * b + 2];
        u32 pos = ws[32 * b + 3];
        double sumconf = ((double)b * (double)cnt + (double)f * (1.0 / 127.0)) * 0.1;
        float denom = fmaxf((float)cnt, 1.0f);
        bool ne = cnt > 0u;
        out[b]      = ne ? ((float)pos / denom) : 0.0f;
        out[NB + b] = ne ? (float)(sumconf / (double)denom) : 0.0f;
    }
}

extern "C" void kernel_launch(void* const* d_in, const int* in_sizes, int n_in,
                              void* d_out, int out_size, void* d_ws, size_t ws_size,
                              hipStream_t stream) {
    const float* logits = (const float*)d_in[0];
    const int*   labels = (const int*)d_in[1];
    float* out = (float*)d_out;
    u32*   ws  = (u32*)d_ws;
    long long n = (long long)in_sizes[0];

    rd_zero_ws<<<1, 512, 0, stream>>>(ws);
    rd_hist<<<BLOCKS, TPB, 0, stream>>>(logits, labels, ws, n);
    rd_finalize<<<1, 64, 0, stream>>>(ws, out);
}